// Round 8
// baseline (316.233 us; speedup 1.0000x reference)
//
#include <hip/hip_runtime.h>
#include <hip/hip_bf16.h>

// CompGCNConv restructured:
//   H_W = ent @ W.T precomputed via fp16-split MFMA (hi/lo two-term split, fp32 acc).
//   HO/HI stored FP16. CSR fill uses XCD-cohort node ownership.
//   Gather: 2-edge-per-wave lane split (half4/lane H, float4/lane R) -> half the
//   VMEM instructions, double the bytes in flight (it was VMEM-issue bound).

#define D 128

typedef _Float16 half8 __attribute__((ext_vector_type(8)));
typedef _Float16 half4t __attribute__((ext_vector_type(4)));
typedef float f32x4 __attribute__((ext_vector_type(4)));

// ---------------- convert 3 weight matrices into fragment-major hi/lo ----------------
// Layout: frag[w][ct][c][lane][8] halfs, lane=(kg<<4)|r16 reads
//   W[w][ct*16 + r16][kg*8 + c*32 + j]   (matches MFMA A/B fragment ownership)
__global__ __launch_bounds__(256) void convert_w_kernel(
    const float* __restrict__ W0, const float* __restrict__ W1, const float* __restrict__ W2,
    _Float16* __restrict__ hi, _Float16* __restrict__ lo)
{
    const int i = (int)(blockIdx.x * blockDim.x + threadIdx.x);   // 6144 slots
    if (i >= 3 * 2048) return;
    const int w    = i >> 11;           // /2048
    const int rem  = i & 2047;          // ct*256 + c*64 + lane
    const int lane = rem & 63;
    const int cc   = (rem >> 6) & 3;
    const int ct   = rem >> 8;
    const int r16  = lane & 15, kg = lane >> 4;
    const float* __restrict__ src = (w == 0) ? W0 : (w == 1) ? W1 : W2;
    const int row = ct * 16 + r16;
    const int col = kg * 8 + cc * 32;
    const float4* s4 = reinterpret_cast<const float4*>(src + row * 128 + col);
    float4 a = s4[0], b = s4[1];
    float v[8] = {a.x, a.y, a.z, a.w, b.x, b.y, b.z, b.w};
    half8 h, l;
    #pragma unroll
    for (int j = 0; j < 8; ++j) {
        _Float16 hh = (_Float16)v[j];
        h[j] = hh;
        l[j] = (_Float16)(v[j] - (float)hh);
    }
    *reinterpret_cast<half8*>(hi + (size_t)i * 8) = h;
    *reinterpret_cast<half8*>(lo + (size_t)i * 8) = l;
}

// ---------------- MFMA triple GEMM: C0 fp32 (self-loop), C1/C2 fp16 (HO/HI) ----------------
__global__ __launch_bounds__(256) void gemm3_mfma_kernel(
    const float* __restrict__ A,
    const _Float16* __restrict__ Wh, const _Float16* __restrict__ Wl,   // frag-major [3][8][4][64][8]
    float* __restrict__ C0, _Float16* __restrict__ C1, _Float16* __restrict__ C2, int M)
{
    __shared__ float sA[64][132];
    const int tid  = threadIdx.x;
    const int lane = tid & 63;
    const int wave = tid >> 6;
    const int rowBase = blockIdx.x * 64 + wave * 16;
    const int r16 = lane & 15;          // A row within tile / output col within tile
    const int kg  = lane >> 4;          // k-group 0..3 (8 consecutive k each)

    // coalesced stage of the 64x128 fp32 A tile (zeros past M)
    #pragma unroll
    for (int i = 0; i < 8; ++i) {
        int idx = tid + i * 256;
        int r = idx >> 5, c = (idx & 31) << 2;
        int gr = blockIdx.x * 64 + r;
        float4 a = make_float4(0.f, 0.f, 0.f, 0.f);
        if (gr < M) a = reinterpret_cast<const float4*>(A)[gr * 32 + (idx & 31)];
        *reinterpret_cast<float4*>(&sA[r][c]) = a;
    }
    __syncthreads();

    // per-wave fragment read from LDS + hi/lo split (held in regs for all 3 matrices)
    const int lrow = wave * 16 + r16;
    half8 a_hi[4], a_lo[4];
    #pragma unroll
    for (int c = 0; c < 4; ++c) {
        const float* ap = &sA[lrow][kg * 8 + c * 32];
        half8 h, l;
        #pragma unroll
        for (int j = 0; j < 8; ++j) {
            float vf = ap[j];
            _Float16 hh = (_Float16)vf;
            h[j] = hh;
            l[j] = (_Float16)(vf - (float)hh);
        }
        a_hi[c] = h; a_lo[c] = l;
    }

    #pragma unroll
    for (int w = 0; w < 3; ++w) {
        const _Float16* wbh = Wh + (size_t)w * 16384 + lane * 8;
        const _Float16* wbl = Wl + (size_t)w * 16384 + lane * 8;

        #pragma unroll
        for (int ct = 0; ct < 8; ct += 2) {
            // fragment-major: chunk (ct,c) at offset ct*2048 + c*512 (halfs)
            half8 bh0[4], bl0[4], bh1[4], bl1[4];
            #pragma unroll
            for (int c = 0; c < 4; ++c) {
                bh0[c] = *reinterpret_cast<const half8*>(wbh + ct * 2048 + c * 512);
                bl0[c] = *reinterpret_cast<const half8*>(wbl + ct * 2048 + c * 512);
                bh1[c] = *reinterpret_cast<const half8*>(wbh + (ct + 1) * 2048 + c * 512);
                bl1[c] = *reinterpret_cast<const half8*>(wbl + (ct + 1) * 2048 + c * 512);
            }

            f32x4 z = {0.f, 0.f, 0.f, 0.f};
            f32x4 hh0 = z, hl0 = z, lh0 = z, hh1 = z, hl1 = z, lh1 = z;
            #pragma unroll
            for (int c = 0; c < 4; ++c) {
                hh0 = __builtin_amdgcn_mfma_f32_16x16x32_f16(a_hi[c], bh0[c], hh0, 0, 0, 0);
                hh1 = __builtin_amdgcn_mfma_f32_16x16x32_f16(a_hi[c], bh1[c], hh1, 0, 0, 0);
                hl0 = __builtin_amdgcn_mfma_f32_16x16x32_f16(a_hi[c], bl0[c], hl0, 0, 0, 0);
                hl1 = __builtin_amdgcn_mfma_f32_16x16x32_f16(a_hi[c], bl1[c], hl1, 0, 0, 0);
                lh0 = __builtin_amdgcn_mfma_f32_16x16x32_f16(a_lo[c], bh0[c], lh0, 0, 0, 0);
                lh1 = __builtin_amdgcn_mfma_f32_16x16x32_f16(a_lo[c], bh1[c], lh1, 0, 0, 0);
            }
            f32x4 s0 = (hh0 + hl0) + lh0;
            f32x4 s1 = (hh1 + hl1) + lh1;

            // C/D layout: col = lane&15, row = (lane>>4)*4 + reg
            const int col0 = ct * 16 + r16;
            #pragma unroll
            for (int r = 0; r < 4; ++r) {
                int row = rowBase + kg * 4 + r;
                if (row < M) {
                    if (w == 0) {
                        C0[(size_t)row * D + col0]      = s0[r];
                        C0[(size_t)row * D + col0 + 16] = s1[r];
                    } else {
                        _Float16* __restrict__ C16 = (w == 1) ? C1 : C2;
                        C16[(size_t)row * D + col0]      = (_Float16)s0[r];
                        C16[(size_t)row * D + col0 + 16] = (_Float16)s1[r];
                    }
                }
            }
        }
    }
}

// ---------------- fp32 GEMM (small M): Ck = A @ Wk^T, stages A once, 3 weights ----------------
__global__ __launch_bounds__(256) void gemm3_nt_kernel(
    const float* __restrict__ A,
    const float* __restrict__ W0, const float* __restrict__ W1, const float* __restrict__ W2,
    float* __restrict__ C0, float* __restrict__ C1, float* __restrict__ C2, int M)
{
    __shared__ float sA[64][132];
    __shared__ float sW[128][132];
    const int tid = threadIdx.x;
    const int rowBase = blockIdx.x * 64;

    #pragma unroll
    for (int i = 0; i < 8; ++i) {
        int idx = tid + i * 256;
        int r = idx >> 5, c = (idx & 31) << 2;
        int gr = rowBase + r;
        float4 a = make_float4(0.f, 0.f, 0.f, 0.f);
        if (gr < M) a = reinterpret_cast<const float4*>(A)[gr * 32 + (idx & 31)];
        *reinterpret_cast<float4*>(&sA[r][c]) = a;
    }

    const int rg = tid >> 4;
    const int cg = tid & 15;
    const int r0 = rg * 4;

    const float* Ws[3] = {W0, W1, W2};
    float*       Cs[3] = {C0, C1, C2};

    #pragma unroll
    for (int w = 0; w < 3; ++w) {
        const float* __restrict__ W = Ws[w];
        float* __restrict__ C = Cs[w];

        __syncthreads();
        #pragma unroll
        for (int i = 0; i < 16; ++i) {
            int idx = tid + i * 256;
            float4 wv = reinterpret_cast<const float4*>(W)[idx];
            int r = idx >> 5, c = (idx & 31) << 2;
            *reinterpret_cast<float4*>(&sW[r][c]) = wv;
        }
        __syncthreads();

        float acc[4][8] = {};
        #pragma unroll 4
        for (int k = 0; k < 128; k += 4) {
            float4 a[4], wv[8];
            #pragma unroll
            for (int i = 0; i < 4; ++i)
                a[i] = *reinterpret_cast<const float4*>(&sA[r0 + i][k]);
            #pragma unroll
            for (int j = 0; j < 8; ++j)
                wv[j] = *reinterpret_cast<const float4*>(&sW[cg + 16 * j][k]);
            #pragma unroll
            for (int i = 0; i < 4; ++i)
                #pragma unroll
                for (int j = 0; j < 8; ++j) {
                    acc[i][j] += a[i].x * wv[j].x;
                    acc[i][j] += a[i].y * wv[j].y;
                    acc[i][j] += a[i].z * wv[j].z;
                    acc[i][j] += a[i].w * wv[j].w;
                }
        }

        #pragma unroll
        for (int i = 0; i < 4; ++i) {
            int row = rowBase + r0 + i;
            if (row < M) {
                #pragma unroll
                for (int j = 0; j < 8; ++j)
                    C[(size_t)row * D + cg + 16 * j] = acc[i][j];
            }
        }
    }
}

// ---------------- histogram of dst (fwd) and src (inv) ----------------
__global__ __launch_bounds__(256) void hist_kernel(
    const int* __restrict__ eidx, int* __restrict__ cnt_f, int* __restrict__ cnt_i, int E)
{
    const int stride = (int)(gridDim.x * blockDim.x);
    for (int e = (int)(blockIdx.x * blockDim.x + threadIdx.x); e < E; e += stride) {
        __hip_atomic_fetch_add(&cnt_f[eidx[E + e]], 1, __ATOMIC_RELAXED, __HIP_MEMORY_SCOPE_AGENT);
        __hip_atomic_fetch_add(&cnt_i[eidx[e]],     1, __ATOMIC_RELAXED, __HIP_MEMORY_SCOPE_AGENT);
    }
}

// ---------------- hierarchical exclusive scan over concatenated cnt_f||cnt_i (2N) ----------------
__global__ __launch_bounds__(256) void scan_p1_kernel(
    const int* __restrict__ cnt, int* __restrict__ bsum, int total)
{
    __shared__ int s[256];
    const int t = threadIdx.x;
    const int base = blockIdx.x * 512 + t * 2;
    int v0 = (base     < total) ? cnt[base]     : 0;
    int v1 = (base + 1 < total) ? cnt[base + 1] : 0;
    s[t] = v0 + v1;
    __syncthreads();
    #pragma unroll
    for (int d = 128; d > 0; d >>= 1) {
        if (t < d) s[t] += s[t + d];
        __syncthreads();
    }
    if (t == 0) bsum[blockIdx.x] = s[0];
}

__global__ __launch_bounds__(256) void scan_p2_kernel(
    const int* __restrict__ bsum, int* __restrict__ boff, int nb)
{
    __shared__ int s[256];
    const int t = threadIdx.x;
    s[t] = (t < nb) ? bsum[t] : 0;
    __syncthreads();
    #pragma unroll
    for (int d = 1; d < 256; d <<= 1) {
        int v = (t >= d) ? s[t - d] : 0;
        __syncthreads();
        s[t] += v;
        __syncthreads();
    }
    boff[t] = t ? s[t - 1] : 0;   // exclusive
}

__global__ __launch_bounds__(256) void scan_p3_kernel(
    const int* __restrict__ cnt, const int* __restrict__ boff,
    int* __restrict__ off_f, int* __restrict__ cur_f,
    int* __restrict__ off_i, int* __restrict__ cur_i,
    int N, int E)
{
    __shared__ int s[256];
    const int t = threadIdx.x;
    const int total = 2 * N;
    const int base = blockIdx.x * 512 + t * 2;
    int v0 = (base     < total) ? cnt[base]     : 0;
    int v1 = (base + 1 < total) ? cnt[base + 1] : 0;
    s[t] = v0 + v1;
    __syncthreads();
    #pragma unroll
    for (int d = 1; d < 256; d <<= 1) {
        int v = (t >= d) ? s[t - d] : 0;
        __syncthreads();
        s[t] += v;
        __syncthreads();
    }
    int pre = boff[blockIdx.x] + (t ? s[t - 1] : 0);
    if (base < total) {
        int g = base;
        if (g < N) { off_f[g] = pre;         cur_f[g] = pre;         }
        else       { off_i[g - N] = pre - E; cur_i[g - N] = pre - E; }
    }
    if (base + 1 < total) {
        int g = base + 1, p = pre + v0;
        if (g < N) { off_f[g] = p;         cur_f[g] = p;         }
        else       { off_i[g - N] = p - E; cur_i[g - N] = p - E; }
    }
    if (blockIdx.x == 0 && t == 0) { off_f[N] = E; off_i[N] = E; }
}

// ---------------- scatter edges into CSR payload arrays (XCD-cohort ownership) ----------------
// payload = node | (type << 18)   (N < 2^18, R < 2^14)
__global__ __launch_bounds__(256) void fill_kernel(
    const int* __restrict__ eidx, const int* __restrict__ etype,
    int* __restrict__ cur_f, int* __restrict__ cur_i,
    int* __restrict__ pay_f, int* __restrict__ pay_i, int E, int N)
{
    const int r = (int)(blockIdx.x & 7);
    const int lo = (int)((long)N * r / 8);
    const int hi = (int)((long)N * (r + 1) / 8);
    const int start = (int)((blockIdx.x >> 3) * blockDim.x + threadIdx.x);
    const int stride = (int)((gridDim.x >> 3) * blockDim.x);
    for (int e = start; e < E; e += stride) {
        int s = eidx[e];
        int d = eidx[E + e];
        bool wf = (d >= lo) & (d < hi);
        bool wi = (s >= lo) & (s < hi);
        if (wf | wi) {
            int t = etype[e];
            if (wf) {
                int pf = __hip_atomic_fetch_add(&cur_f[d], 1, __ATOMIC_RELAXED, __HIP_MEMORY_SCOPE_AGENT);
                pay_f[pf] = s | (t << 18);
            }
            if (wi) {
                int pi = __hip_atomic_fetch_add(&cur_i[s], 1, __ATOMIC_RELAXED, __HIP_MEMORY_SCOPE_AGENT);
                pay_i[pi] = d | (t << 18);
            }
        }
    }
}

// ---------------- pull-gather: one wave per node, 2-edge lane split ----------------
// Wave halves (32 lanes each) own one edge of a pair. Lane sub=lane&31 covers
// d-chunk [4*sub, 4*sub+4): H read as half4 (8B/lane -> 2 rows/instr), R as
// float4 (16B/lane -> 2 rows/instr). Halves combined via shfl_xor(32) at the end.
__global__ __launch_bounds__(256) void gather_kernel(
    const int* __restrict__ off_f, const int* __restrict__ pay_f,
    const int* __restrict__ off_i, const int* __restrict__ pay_i,
    const _Float16* __restrict__ HO, const _Float16* __restrict__ HI,
    const float* __restrict__ RO, const float* __restrict__ RI,
    float* __restrict__ out, int N)
{
    const int lane = threadIdx.x & 63;
    const int half = lane >> 5;
    const int sub  = lane & 31;
    int node = (int)((blockIdx.x * blockDim.x + threadIdx.x) >> 6);
    if (node >= N) return;                     // wave-uniform
    node = __builtin_amdgcn_readfirstlane(node);

    float4 acc = make_float4(0.f, 0.f, 0.f, 0.f);

    #pragma unroll
    for (int dir = 0; dir < 2; ++dir) {
        const int* __restrict__ off = dir ? off_i : off_f;
        const int* __restrict__ pay = dir ? pay_i : pay_f;
        const _Float16* __restrict__ H = dir ? HI : HO;
        const float* __restrict__ R = dir ? RI : RO;

        const int b = off[node], e = off[node + 1];
        int i = b;
        for (; i + 3 < e; i += 4) {
            unsigned pA = (unsigned)pay[i + half];
            unsigned pB = (unsigned)pay[i + 2 + half];
            half4t hA = *reinterpret_cast<const half4t*>(H + (size_t)(pA & 0x3FFFF) * 128 + sub * 4);
            float4 rA = *reinterpret_cast<const float4*>(R + (size_t)(pA >> 18) * 128 + sub * 4);
            half4t hB = *reinterpret_cast<const half4t*>(H + (size_t)(pB & 0x3FFFF) * 128 + sub * 4);
            float4 rB = *reinterpret_cast<const float4*>(R + (size_t)(pB >> 18) * 128 + sub * 4);
            acc.x += ((float)hA[0] - rA.x) + ((float)hB[0] - rB.x);
            acc.y += ((float)hA[1] - rA.y) + ((float)hB[1] - rB.y);
            acc.z += ((float)hA[2] - rA.z) + ((float)hB[2] - rB.z);
            acc.w += ((float)hA[3] - rA.w) + ((float)hB[3] - rB.w);
        }
        for (; i + 1 < e; i += 2) {
            unsigned p = (unsigned)pay[i + half];
            half4t h = *reinterpret_cast<const half4t*>(H + (size_t)(p & 0x3FFFF) * 128 + sub * 4);
            float4 r = *reinterpret_cast<const float4*>(R + (size_t)(p >> 18) * 128 + sub * 4);
            acc.x += (float)h[0] - r.x;
            acc.y += (float)h[1] - r.y;
            acc.z += (float)h[2] - r.z;
            acc.w += (float)h[3] - r.w;
        }
        if (i < e) {                              // odd tail: half 0 only
            unsigned p = (unsigned)pay[i];
            if (half == 0) {
                half4t h = *reinterpret_cast<const half4t*>(H + (size_t)(p & 0x3FFFF) * 128 + sub * 4);
                float4 r = *reinterpret_cast<const float4*>(R + (size_t)(p >> 18) * 128 + sub * 4);
                acc.x += (float)h[0] - r.x;
                acc.y += (float)h[1] - r.y;
                acc.z += (float)h[2] - r.z;
                acc.w += (float)h[3] - r.w;
            }
        }
    }

    // combine the two halves
    acc.x += __shfl_xor(acc.x, 32);
    acc.y += __shfl_xor(acc.y, 32);
    acc.z += __shfl_xor(acc.z, 32);
    acc.w += __shfl_xor(acc.w, 32);

    const int deg = (off_f[node + 1] - off_f[node]) + (off_i[node + 1] - off_i[node]);
    const float inv = 1.0f / (float)(deg > 0 ? deg : 1);
    if (half == 0) {
        float4* op = reinterpret_cast<float4*>(out) + (size_t)node * 32 + sub;
        float4 self = *op;                         // self-loop term (W_S GEMM result)
        self.x = (self.x + acc.x) * inv;
        self.y = (self.y + acc.y) * inv;
        self.z = (self.z + acc.z) * inv;
        self.w = (self.w + acc.w) * inv;
        *op = self;
    }
}

// ---------------- per-column sums of x (already degree-normalized) ----------------
__global__ __launch_bounds__(256) void stats_kernel(
    const float* __restrict__ x,
    float* __restrict__ gsum, float* __restrict__ gsq, int N)
{
    __shared__ float s_sum[256], s_sq[256];
    const int tid = threadIdx.x;
    float lsum = 0.f, lsq = 0.f;
    const int total = N * D;
    const int stride = (int)(gridDim.x * blockDim.x);   // multiple of 128
    for (int e = (int)(blockIdx.x * blockDim.x) + tid; e < total; e += stride) {
        float v = x[e];
        lsum += v;
        lsq += v * v;
    }
    s_sum[tid] = lsum;
    s_sq[tid] = lsq;
    __syncthreads();
    if (tid < 128) {
        __hip_atomic_fetch_add(&gsum[tid], s_sum[tid] + s_sum[tid + 128], __ATOMIC_RELAXED, __HIP_MEMORY_SCOPE_AGENT);
        __hip_atomic_fetch_add(&gsq[tid],  s_sq[tid]  + s_sq[tid + 128],  __ATOMIC_RELAXED, __HIP_MEMORY_SCOPE_AGENT);
    }
}

// ---------------- BN (batch stats, biased var) + ReLU, in place ----------------
__global__ __launch_bounds__(256) void bn_relu_kernel(
    float* __restrict__ out,
    const float* __restrict__ gsum, const float* __restrict__ gsq,
    const float* __restrict__ gamma, const float* __restrict__ beta,
    int N)
{
    const int total4 = N * (D / 4);
    const int stride = (int)(gridDim.x * blockDim.x);
    const float invN = 1.0f / (float)N;
    for (int e4 = (int)(blockIdx.x * blockDim.x + threadIdx.x); e4 < total4; e4 += stride) {
        int c0 = (e4 & 31) << 2;
        float4 v = reinterpret_cast<float4*>(out)[e4];
        float r[4] = {v.x, v.y, v.z, v.w};
        #pragma unroll
        for (int j = 0; j < 4; ++j) {
            int c = c0 + j;
            float mean = gsum[c] * invN;
            float var = gsq[c] * invN - mean * mean;
            float y = (r[j] - mean) * rsqrtf(var + 1e-5f) * gamma[c] + beta[c];
            r[j] = y > 0.f ? y : 0.f;
        }
        reinterpret_cast<float4*>(out)[e4] = make_float4(r[0], r[1], r[2], r[3]);
    }
}

extern "C" void kernel_launch(void* const* d_in, const int* in_sizes, int n_in,
                              void* d_out, int out_size, void* d_ws, size_t ws_size,
                              hipStream_t stream) {
    const float* ent   = (const float*)d_in[0];
    const float* rel   = (const float*)d_in[1];
    const int*   eidx  = (const int*)d_in[2];
    const int*   etype = (const int*)d_in[3];
    const float* W_O   = (const float*)d_in[4];
    const float* W_I   = (const float*)d_in[5];
    const float* W_S   = (const float*)d_in[6];
    const float* W_rel = (const float*)d_in[7];
    const float* gamma = (const float*)d_in[8];
    const float* beta  = (const float*)d_in[9];

    const int N = in_sizes[0] / D;     // 50000
    const int R = in_sizes[1] / D;     // 200
    const int E = in_sizes[3];         // 600000

    float* outp = (float*)d_out;       // [N*D] out  +  [R*D] new_rel
    float* acc  = outp;                // self-loop accumulator lives in d_out

    // workspace layout (4-byte words unless noted)
    _Float16* HO = (_Float16*)d_ws;            // N*D halfs
    _Float16* HI = HO + (size_t)N * D;         // N*D halfs
    float* RO    = (float*)(HI + (size_t)N * D); // R*D fp32
    float* RI    = RO + (size_t)R * D;         // R*D fp32
    int*   off_f = (int*)(RI + (size_t)R * D); // N+1
    int*   off_i = off_f + (N + 1);            // N+1
    int*   cur_f = off_i + (N + 1);            // N
    int*   cur_i = cur_f + N;                  // N
    int*   pay_f = cur_i + N;                  // E
    int*   pay_i = pay_f + E;                  // E
    int*   cnt_f = pay_i + E;                  // N   (zeroed region starts here; cnt_i contiguous)
    int*   cnt_i = cnt_f + N;                  // N
    float* gsum  = (float*)(cnt_i + N);        // 128
    float* gsq   = gsum + D;                   // 128
    int*   bsum  = (int*)(gsq + D);            // 256
    int*   boff  = bsum + 256;                 // 256
    // fp16 weight split arrays (16B aligned: word offset rounded to multiple of 4)
    size_t woff = (size_t)(boff + 256 - (int*)d_ws);
    woff = (woff + 3) & ~(size_t)3;
    _Float16* Wh = (_Float16*)((int*)d_ws + woff);   // 3*128*128 halfs, fragment-major
    _Float16* Wl = Wh + 3 * 16384;                   // 3*128*128 halfs, fragment-major

    // zero counts + stats every call (single contiguous memset)
    hipMemsetAsync(cnt_f, 0, (size_t)(2 * N + 2 * D) * sizeof(float), stream);

    // fp16 hi/lo conversion of the 3 entity-side weight matrices (W_S, W_O, W_I)
    convert_w_kernel<<<24, 256, 0, stream>>>(W_S, W_O, W_I, Wh, Wl);

    // MFMA triple GEMM (LDS-staged A, frag-major B): self-loop fp32 into out acc,
    // HO/HI stored fp16 for the bandwidth-bound gather
    const int gemm_grid_ent = (N + 63) / 64;
    gemm3_mfma_kernel<<<gemm_grid_ent, 256, 0, stream>>>(ent, Wh, Wl, acc, HO, HI, N);

    // relation projections (tiny, fp32 path) + new_rel_emb output
    const int gemm_grid_rel = (R + 63) / 64;
    gemm3_nt_kernel<<<gemm_grid_rel, 256, 0, stream>>>(rel, W_O, W_I, W_rel,
                                                       RO, RI, outp + (size_t)N * D, R);

    // CSR build: histogram -> hierarchical scan -> XCD-cohort fill
    hist_kernel<<<1024, 256, 0, stream>>>(eidx, cnt_f, cnt_i, E);
    const int scan_blocks = (2 * N + 511) / 512;   // 196 for N=50000 (must be <= 256)
    scan_p1_kernel<<<scan_blocks, 256, 0, stream>>>(cnt_f, bsum, 2 * N);
    scan_p2_kernel<<<1, 256, 0, stream>>>(bsum, boff, scan_blocks);
    scan_p3_kernel<<<scan_blocks, 256, 0, stream>>>(cnt_f, boff,
                                                    off_f, cur_f, off_i, cur_i, N, E);
    fill_kernel<<<2048, 256, 0, stream>>>(eidx, etype, cur_f, cur_i, pay_f, pay_i, E, N);

    // pull-gather (one wave per node) -> degree-normalized pre-BN x in d_out
    const int gather_blocks = (int)(((size_t)N * 64 + 255) / 256);
    gather_kernel<<<gather_blocks, 256, 0, stream>>>(
        off_f, pay_f, off_i, pay_i, HO, HI, RO, RI, acc, N);

    // column stats of x
    stats_kernel<<<1024, 256, 0, stream>>>(acc, gsum, gsq, N);

    // BN + ReLU in place
    bn_relu_kernel<<<2048, 256, 0, stream>>>(outp, gsum, gsq, gamma, beta, N);
}

// Round 9
// 311.480 us; speedup vs baseline: 1.0153x; 1.0153x over previous
//
#include <hip/hip_runtime.h>
#include <hip/hip_bf16.h>

// CompGCNConv restructured:
//   H_W = ent @ W.T precomputed via fp16-split MFMA (hi/lo two-term split, fp32 acc).
//   HO/HI stored FP16. CSR fill uses XCD-cohort node ownership.
//   Gather: payload pre-loaded 64-at-a-time into a register (one coalesced load),
//   broadcast via readlane -> SGPR row bases, pure back-to-back H/R loads (the
//   per-iteration dependent pay-load chain was the gather bottleneck).

#define D 128

typedef _Float16 half8 __attribute__((ext_vector_type(8)));
typedef _Float16 half2t __attribute__((ext_vector_type(2)));
typedef float f32x4 __attribute__((ext_vector_type(4)));

// ---------------- convert 3 weight matrices into fragment-major hi/lo ----------------
// Layout: frag[w][ct][c][lane][8] halfs, lane=(kg<<4)|r16 reads
//   W[w][ct*16 + r16][kg*8 + c*32 + j]   (matches MFMA A/B fragment ownership)
__global__ __launch_bounds__(256) void convert_w_kernel(
    const float* __restrict__ W0, const float* __restrict__ W1, const float* __restrict__ W2,
    _Float16* __restrict__ hi, _Float16* __restrict__ lo)
{
    const int i = (int)(blockIdx.x * blockDim.x + threadIdx.x);   // 6144 slots
    if (i >= 3 * 2048) return;
    const int w    = i >> 11;           // /2048
    const int rem  = i & 2047;          // ct*256 + c*64 + lane
    const int lane = rem & 63;
    const int cc   = (rem >> 6) & 3;
    const int ct   = rem >> 8;
    const int r16  = lane & 15, kg = lane >> 4;
    const float* __restrict__ src = (w == 0) ? W0 : (w == 1) ? W1 : W2;
    const int row = ct * 16 + r16;
    const int col = kg * 8 + cc * 32;
    const float4* s4 = reinterpret_cast<const float4*>(src + row * 128 + col);
    float4 a = s4[0], b = s4[1];
    float v[8] = {a.x, a.y, a.z, a.w, b.x, b.y, b.z, b.w};
    half8 h, l;
    #pragma unroll
    for (int j = 0; j < 8; ++j) {
        _Float16 hh = (_Float16)v[j];
        h[j] = hh;
        l[j] = (_Float16)(v[j] - (float)hh);
    }
    *reinterpret_cast<half8*>(hi + (size_t)i * 8) = h;
    *reinterpret_cast<half8*>(lo + (size_t)i * 8) = l;
}

// ---------------- MFMA triple GEMM: C0 fp32 (self-loop), C1/C2 fp16 (HO/HI) ----------------
__global__ __launch_bounds__(256) void gemm3_mfma_kernel(
    const float* __restrict__ A,
    const _Float16* __restrict__ Wh, const _Float16* __restrict__ Wl,   // frag-major [3][8][4][64][8]
    float* __restrict__ C0, _Float16* __restrict__ C1, _Float16* __restrict__ C2, int M)
{
    __shared__ float sA[64][132];
    const int tid  = threadIdx.x;
    const int lane = tid & 63;
    const int wave = tid >> 6;
    const int rowBase = blockIdx.x * 64 + wave * 16;
    const int r16 = lane & 15;          // A row within tile / output col within tile
    const int kg  = lane >> 4;          // k-group 0..3 (8 consecutive k each)

    // coalesced stage of the 64x128 fp32 A tile (zeros past M)
    #pragma unroll
    for (int i = 0; i < 8; ++i) {
        int idx = tid + i * 256;
        int r = idx >> 5, c = (idx & 31) << 2;
        int gr = blockIdx.x * 64 + r;
        float4 a = make_float4(0.f, 0.f, 0.f, 0.f);
        if (gr < M) a = reinterpret_cast<const float4*>(A)[gr * 32 + (idx & 31)];
        *reinterpret_cast<float4*>(&sA[r][c]) = a;
    }
    __syncthreads();

    // per-wave fragment read from LDS + hi/lo split (held in regs for all 3 matrices)
    const int lrow = wave * 16 + r16;
    half8 a_hi[4], a_lo[4];
    #pragma unroll
    for (int c = 0; c < 4; ++c) {
        const float* ap = &sA[lrow][kg * 8 + c * 32];
        half8 h, l;
        #pragma unroll
        for (int j = 0; j < 8; ++j) {
            float vf = ap[j];
            _Float16 hh = (_Float16)vf;
            h[j] = hh;
            l[j] = (_Float16)(vf - (float)hh);
        }
        a_hi[c] = h; a_lo[c] = l;
    }

    #pragma unroll
    for (int w = 0; w < 3; ++w) {
        const _Float16* wbh = Wh + (size_t)w * 16384 + lane * 8;
        const _Float16* wbl = Wl + (size_t)w * 16384 + lane * 8;

        #pragma unroll
        for (int ct = 0; ct < 8; ct += 2) {
            // fragment-major: chunk (ct,c) at offset ct*2048 + c*512 (halfs)
            half8 bh0[4], bl0[4], bh1[4], bl1[4];
            #pragma unroll
            for (int c = 0; c < 4; ++c) {
                bh0[c] = *reinterpret_cast<const half8*>(wbh + ct * 2048 + c * 512);
                bl0[c] = *reinterpret_cast<const half8*>(wbl + ct * 2048 + c * 512);
                bh1[c] = *reinterpret_cast<const half8*>(wbh + (ct + 1) * 2048 + c * 512);
                bl1[c] = *reinterpret_cast<const half8*>(wbl + (ct + 1) * 2048 + c * 512);
            }

            f32x4 z = {0.f, 0.f, 0.f, 0.f};
            f32x4 hh0 = z, hl0 = z, lh0 = z, hh1 = z, hl1 = z, lh1 = z;
            #pragma unroll
            for (int c = 0; c < 4; ++c) {
                hh0 = __builtin_amdgcn_mfma_f32_16x16x32_f16(a_hi[c], bh0[c], hh0, 0, 0, 0);
                hh1 = __builtin_amdgcn_mfma_f32_16x16x32_f16(a_hi[c], bh1[c], hh1, 0, 0, 0);
                hl0 = __builtin_amdgcn_mfma_f32_16x16x32_f16(a_hi[c], bl0[c], hl0, 0, 0, 0);
                hl1 = __builtin_amdgcn_mfma_f32_16x16x32_f16(a_hi[c], bl1[c], hl1, 0, 0, 0);
                lh0 = __builtin_amdgcn_mfma_f32_16x16x32_f16(a_lo[c], bh0[c], lh0, 0, 0, 0);
                lh1 = __builtin_amdgcn_mfma_f32_16x16x32_f16(a_lo[c], bh1[c], lh1, 0, 0, 0);
            }
            f32x4 s0 = (hh0 + hl0) + lh0;
            f32x4 s1 = (hh1 + hl1) + lh1;

            // C/D layout: col = lane&15, row = (lane>>4)*4 + reg
            const int col0 = ct * 16 + r16;
            #pragma unroll
            for (int r = 0; r < 4; ++r) {
                int row = rowBase + kg * 4 + r;
                if (row < M) {
                    if (w == 0) {
                        C0[(size_t)row * D + col0]      = s0[r];
                        C0[(size_t)row * D + col0 + 16] = s1[r];
                    } else {
                        _Float16* __restrict__ C16 = (w == 1) ? C1 : C2;
                        C16[(size_t)row * D + col0]      = (_Float16)s0[r];
                        C16[(size_t)row * D + col0 + 16] = (_Float16)s1[r];
                    }
                }
            }
        }
    }
}

// ---------------- fp32 GEMM (small M): Ck = A @ Wk^T, stages A once, 3 weights ----------------
__global__ __launch_bounds__(256) void gemm3_nt_kernel(
    const float* __restrict__ A,
    const float* __restrict__ W0, const float* __restrict__ W1, const float* __restrict__ W2,
    float* __restrict__ C0, float* __restrict__ C1, float* __restrict__ C2, int M)
{
    __shared__ float sA[64][132];
    __shared__ float sW[128][132];
    const int tid = threadIdx.x;
    const int rowBase = blockIdx.x * 64;

    #pragma unroll
    for (int i = 0; i < 8; ++i) {
        int idx = tid + i * 256;
        int r = idx >> 5, c = (idx & 31) << 2;
        int gr = rowBase + r;
        float4 a = make_float4(0.f, 0.f, 0.f, 0.f);
        if (gr < M) a = reinterpret_cast<const float4*>(A)[gr * 32 + (idx & 31)];
        *reinterpret_cast<float4*>(&sA[r][c]) = a;
    }

    const int rg = tid >> 4;
    const int cg = tid & 15;
    const int r0 = rg * 4;

    const float* Ws[3] = {W0, W1, W2};
    float*       Cs[3] = {C0, C1, C2};

    #pragma unroll
    for (int w = 0; w < 3; ++w) {
        const float* __restrict__ W = Ws[w];
        float* __restrict__ C = Cs[w];

        __syncthreads();
        #pragma unroll
        for (int i = 0; i < 16; ++i) {
            int idx = tid + i * 256;
            float4 wv = reinterpret_cast<const float4*>(W)[idx];
            int r = idx >> 5, c = (idx & 31) << 2;
            *reinterpret_cast<float4*>(&sW[r][c]) = wv;
        }
        __syncthreads();

        float acc[4][8] = {};
        #pragma unroll 4
        for (int k = 0; k < 128; k += 4) {
            float4 a[4], wv[8];
            #pragma unroll
            for (int i = 0; i < 4; ++i)
                a[i] = *reinterpret_cast<const float4*>(&sA[r0 + i][k]);
            #pragma unroll
            for (int j = 0; j < 8; ++j)
                wv[j] = *reinterpret_cast<const float4*>(&sW[cg + 16 * j][k]);
            #pragma unroll
            for (int i = 0; i < 4; ++i)
                #pragma unroll
                for (int j = 0; j < 8; ++j) {
                    acc[i][j] += a[i].x * wv[j].x;
                    acc[i][j] += a[i].y * wv[j].y;
                    acc[i][j] += a[i].z * wv[j].z;
                    acc[i][j] += a[i].w * wv[j].w;
                }
        }

        #pragma unroll
        for (int i = 0; i < 4; ++i) {
            int row = rowBase + r0 + i;
            if (row < M) {
                #pragma unroll
                for (int j = 0; j < 8; ++j)
                    C[(size_t)row * D + cg + 16 * j] = acc[i][j];
            }
        }
    }
}

// ---------------- histogram of dst (fwd) and src (inv) ----------------
__global__ __launch_bounds__(256) void hist_kernel(
    const int* __restrict__ eidx, int* __restrict__ cnt_f, int* __restrict__ cnt_i, int E)
{
    const int stride = (int)(gridDim.x * blockDim.x);
    for (int e = (int)(blockIdx.x * blockDim.x + threadIdx.x); e < E; e += stride) {
        __hip_atomic_fetch_add(&cnt_f[eidx[E + e]], 1, __ATOMIC_RELAXED, __HIP_MEMORY_SCOPE_AGENT);
        __hip_atomic_fetch_add(&cnt_i[eidx[e]],     1, __ATOMIC_RELAXED, __HIP_MEMORY_SCOPE_AGENT);
    }
}

// ---------------- hierarchical exclusive scan over concatenated cnt_f||cnt_i (2N) ----------------
__global__ __launch_bounds__(256) void scan_p1_kernel(
    const int* __restrict__ cnt, int* __restrict__ bsum, int total)
{
    __shared__ int s[256];
    const int t = threadIdx.x;
    const int base = blockIdx.x * 512 + t * 2;
    int v0 = (base     < total) ? cnt[base]     : 0;
    int v1 = (base + 1 < total) ? cnt[base + 1] : 0;
    s[t] = v0 + v1;
    __syncthreads();
    #pragma unroll
    for (int d = 128; d > 0; d >>= 1) {
        if (t < d) s[t] += s[t + d];
        __syncthreads();
    }
    if (t == 0) bsum[blockIdx.x] = s[0];
}

__global__ __launch_bounds__(256) void scan_p2_kernel(
    const int* __restrict__ bsum, int* __restrict__ boff, int nb)
{
    __shared__ int s[256];
    const int t = threadIdx.x;
    s[t] = (t < nb) ? bsum[t] : 0;
    __syncthreads();
    #pragma unroll
    for (int d = 1; d < 256; d <<= 1) {
        int v = (t >= d) ? s[t - d] : 0;
        __syncthreads();
        s[t] += v;
        __syncthreads();
    }
    boff[t] = t ? s[t - 1] : 0;   // exclusive
}

__global__ __launch_bounds__(256) void scan_p3_kernel(
    const int* __restrict__ cnt, const int* __restrict__ boff,
    int* __restrict__ off_f, int* __restrict__ cur_f,
    int* __restrict__ off_i, int* __restrict__ cur_i,
    int N, int E)
{
    __shared__ int s[256];
    const int t = threadIdx.x;
    const int total = 2 * N;
    const int base = blockIdx.x * 512 + t * 2;
    int v0 = (base     < total) ? cnt[base]     : 0;
    int v1 = (base + 1 < total) ? cnt[base + 1] : 0;
    s[t] = v0 + v1;
    __syncthreads();
    #pragma unroll
    for (int d = 1; d < 256; d <<= 1) {
        int v = (t >= d) ? s[t - d] : 0;
        __syncthreads();
        s[t] += v;
        __syncthreads();
    }
    int pre = boff[blockIdx.x] + (t ? s[t - 1] : 0);
    if (base < total) {
        int g = base;
        if (g < N) { off_f[g] = pre;         cur_f[g] = pre;         }
        else       { off_i[g - N] = pre - E; cur_i[g - N] = pre - E; }
    }
    if (base + 1 < total) {
        int g = base + 1, p = pre + v0;
        if (g < N) { off_f[g] = p;         cur_f[g] = p;         }
        else       { off_i[g - N] = p - E; cur_i[g - N] = p - E; }
    }
    if (blockIdx.x == 0 && t == 0) { off_f[N] = E; off_i[N] = E; }
}

// ---------------- scatter edges into CSR payload arrays (XCD-cohort ownership) ----------------
// payload = node | (type << 18)   (N < 2^18, R < 2^14)
__global__ __launch_bounds__(256) void fill_kernel(
    const int* __restrict__ eidx, const int* __restrict__ etype,
    int* __restrict__ cur_f, int* __restrict__ cur_i,
    int* __restrict__ pay_f, int* __restrict__ pay_i, int E, int N)
{
    const int r = (int)(blockIdx.x & 7);
    const int lo = (int)((long)N * r / 8);
    const int hi = (int)((long)N * (r + 1) / 8);
    const int start = (int)((blockIdx.x >> 3) * blockDim.x + threadIdx.x);
    const int stride = (int)((gridDim.x >> 3) * blockDim.x);
    for (int e = start; e < E; e += stride) {
        int s = eidx[e];
        int d = eidx[E + e];
        bool wf = (d >= lo) & (d < hi);
        bool wi = (s >= lo) & (s < hi);
        if (wf | wi) {
            int t = etype[e];
            if (wf) {
                int pf = __hip_atomic_fetch_add(&cur_f[d], 1, __ATOMIC_RELAXED, __HIP_MEMORY_SCOPE_AGENT);
                pay_f[pf] = s | (t << 18);
            }
            if (wi) {
                int pi = __hip_atomic_fetch_add(&cur_i[s], 1, __ATOMIC_RELAXED, __HIP_MEMORY_SCOPE_AGENT);
                pay_i[pi] = d | (t << 18);
            }
        }
    }
}

// ---------------- pull-gather: one wave per node, readlane-broadcast payload ----------------
// Per 64-edge chunk: ONE coalesced load of pay[b+lane] into a register; payloads
// extracted via readlane (SGPR, no memory latency) -> H/R loads issue back-to-back
// from scalar bases. 4-edge unrolled = 8 independent loads in flight per wave.
__global__ __launch_bounds__(256) void gather_kernel(
    const int* __restrict__ off_f, const int* __restrict__ pay_f,
    const int* __restrict__ off_i, const int* __restrict__ pay_i,
    const _Float16* __restrict__ HO, const _Float16* __restrict__ HI,
    const float* __restrict__ RO, const float* __restrict__ RI,
    float* __restrict__ out, int N)
{
    const int lane = threadIdx.x & 63;
    int node = (int)((blockIdx.x * blockDim.x + threadIdx.x) >> 6);
    if (node >= N) return;                     // wave-uniform
    node = __builtin_amdgcn_readfirstlane(node);

    float2* __restrict__ out2 = reinterpret_cast<float2*>(out);
    float2 sum = out2[(size_t)node * 64 + lane];   // self-loop term (W_S GEMM result)

    const int bf = off_f[node], ef = off_f[node + 1];
    const int bi = off_i[node], ei = off_i[node + 1];

    #pragma unroll
    for (int dir = 0; dir < 2; ++dir) {
        const int b = dir ? bi : bf;
        const int e = dir ? ei : ef;
        const int* __restrict__ pay = dir ? pay_i : pay_f;
        const _Float16* __restrict__ H = dir ? HI : HO;
        const float* __restrict__ R = dir ? RI : RO;

        for (int base = b; base < e; base += 64) {
            int pv = 0;
            if (base + lane < e) pv = pay[base + lane];
            const int rem = e - base;
            const int len = rem < 64 ? rem : 64;

            int i = 0;
            for (; i + 3 < len; i += 4) {
                unsigned p0 = (unsigned)__builtin_amdgcn_readlane(pv, i);
                unsigned p1 = (unsigned)__builtin_amdgcn_readlane(pv, i + 1);
                unsigned p2 = (unsigned)__builtin_amdgcn_readlane(pv, i + 2);
                unsigned p3 = (unsigned)__builtin_amdgcn_readlane(pv, i + 3);
                half2t h0 = *reinterpret_cast<const half2t*>(H + (size_t)(p0 & 0x3FFFF) * 128 + lane * 2);
                float2 r0 = *reinterpret_cast<const float2*>(R + (size_t)(p0 >> 18) * 128 + lane * 2);
                half2t h1 = *reinterpret_cast<const half2t*>(H + (size_t)(p1 & 0x3FFFF) * 128 + lane * 2);
                float2 r1 = *reinterpret_cast<const float2*>(R + (size_t)(p1 >> 18) * 128 + lane * 2);
                half2t h2 = *reinterpret_cast<const half2t*>(H + (size_t)(p2 & 0x3FFFF) * 128 + lane * 2);
                float2 r2 = *reinterpret_cast<const float2*>(R + (size_t)(p2 >> 18) * 128 + lane * 2);
                half2t h3 = *reinterpret_cast<const half2t*>(H + (size_t)(p3 & 0x3FFFF) * 128 + lane * 2);
                float2 r3 = *reinterpret_cast<const float2*>(R + (size_t)(p3 >> 18) * 128 + lane * 2);
                sum.x += (((float)h0[0] - r0.x) + ((float)h1[0] - r1.x))
                       + (((float)h2[0] - r2.x) + ((float)h3[0] - r3.x));
                sum.y += (((float)h0[1] - r0.y) + ((float)h1[1] - r1.y))
                       + (((float)h2[1] - r2.y) + ((float)h3[1] - r3.y));
            }
            for (; i < len; ++i) {
                unsigned p = (unsigned)__builtin_amdgcn_readlane(pv, i);
                half2t h = *reinterpret_cast<const half2t*>(H + (size_t)(p & 0x3FFFF) * 128 + lane * 2);
                float2 r = *reinterpret_cast<const float2*>(R + (size_t)(p >> 18) * 128 + lane * 2);
                sum.x += (float)h[0] - r.x;
                sum.y += (float)h[1] - r.y;
            }
        }
    }

    const int deg = (ef - bf) + (ei - bi);
    const float inv = 1.0f / (float)(deg > 0 ? deg : 1);
    sum.x *= inv;
    sum.y *= inv;
    out2[(size_t)node * 64 + lane] = sum;
}

// ---------------- per-column sums of x (already degree-normalized) ----------------
__global__ __launch_bounds__(256) void stats_kernel(
    const float* __restrict__ x,
    float* __restrict__ gsum, float* __restrict__ gsq, int N)
{
    __shared__ float s_sum[256], s_sq[256];
    const int tid = threadIdx.x;
    float lsum = 0.f, lsq = 0.f;
    const int total = N * D;
    const int stride = (int)(gridDim.x * blockDim.x);   // multiple of 128
    for (int e = (int)(blockIdx.x * blockDim.x) + tid; e < total; e += stride) {
        float v = x[e];
        lsum += v;
        lsq += v * v;
    }
    s_sum[tid] = lsum;
    s_sq[tid] = lsq;
    __syncthreads();
    if (tid < 128) {
        __hip_atomic_fetch_add(&gsum[tid], s_sum[tid] + s_sum[tid + 128], __ATOMIC_RELAXED, __HIP_MEMORY_SCOPE_AGENT);
        __hip_atomic_fetch_add(&gsq[tid],  s_sq[tid]  + s_sq[tid + 128],  __ATOMIC_RELAXED, __HIP_MEMORY_SCOPE_AGENT);
    }
}

// ---------------- BN (batch stats, biased var) + ReLU, in place ----------------
__global__ __launch_bounds__(256) void bn_relu_kernel(
    float* __restrict__ out,
    const float* __restrict__ gsum, const float* __restrict__ gsq,
    const float* __restrict__ gamma, const float* __restrict__ beta,
    int N)
{
    const int total4 = N * (D / 4);
    const int stride = (int)(gridDim.x * blockDim.x);
    const float invN = 1.0f / (float)N;
    for (int e4 = (int)(blockIdx.x * blockDim.x + threadIdx.x); e4 < total4; e4 += stride) {
        int c0 = (e4 & 31) << 2;
        float4 v = reinterpret_cast<float4*>(out)[e4];
        float r[4] = {v.x, v.y, v.z, v.w};
        #pragma unroll
        for (int j = 0; j < 4; ++j) {
            int c = c0 + j;
            float mean = gsum[c] * invN;
            float var = gsq[c] * invN - mean * mean;
            float y = (r[j] - mean) * rsqrtf(var + 1e-5f) * gamma[c] + beta[c];
            r[j] = y > 0.f ? y : 0.f;
        }
        reinterpret_cast<float4*>(out)[e4] = make_float4(r[0], r[1], r[2], r[3]);
    }
}

extern "C" void kernel_launch(void* const* d_in, const int* in_sizes, int n_in,
                              void* d_out, int out_size, void* d_ws, size_t ws_size,
                              hipStream_t stream) {
    const float* ent   = (const float*)d_in[0];
    const float* rel   = (const float*)d_in[1];
    const int*   eidx  = (const int*)d_in[2];
    const int*   etype = (const int*)d_in[3];
    const float* W_O   = (const float*)d_in[4];
    const float* W_I   = (const float*)d_in[5];
    const float* W_S   = (const float*)d_in[6];
    const float* W_rel = (const float*)d_in[7];
    const float* gamma = (const float*)d_in[8];
    const float* beta  = (const float*)d_in[9];

    const int N = in_sizes[0] / D;     // 50000
    const int R = in_sizes[1] / D;     // 200
    const int E = in_sizes[3];         // 600000

    float* outp = (float*)d_out;       // [N*D] out  +  [R*D] new_rel
    float* acc  = outp;                // self-loop accumulator lives in d_out

    // workspace layout (4-byte words unless noted)
    _Float16* HO = (_Float16*)d_ws;            // N*D halfs
    _Float16* HI = HO + (size_t)N * D;         // N*D halfs
    float* RO    = (float*)(HI + (size_t)N * D); // R*D fp32
    float* RI    = RO + (size_t)R * D;         // R*D fp32
    int*   off_f = (int*)(RI + (size_t)R * D); // N+1
    int*   off_i = off_f + (N + 1);            // N+1
    int*   cur_f = off_i + (N + 1);            // N
    int*   cur_i = cur_f + N;                  // N
    int*   pay_f = cur_i + N;                  // E
    int*   pay_i = pay_f + E;                  // E
    int*   cnt_f = pay_i + E;                  // N   (zeroed region starts here; cnt_i contiguous)
    int*   cnt_i = cnt_f + N;                  // N
    float* gsum  = (float*)(cnt_i + N);        // 128
    float* gsq   = gsum + D;                   // 128
    int*   bsum  = (int*)(gsq + D);            // 256
    int*   boff  = bsum + 256;                 // 256
    // fp16 weight split arrays (16B aligned: word offset rounded to multiple of 4)
    size_t woff = (size_t)(boff + 256 - (int*)d_ws);
    woff = (woff + 3) & ~(size_t)3;
    _Float16* Wh = (_Float16*)((int*)d_ws + woff);   // 3*128*128 halfs, fragment-major
    _Float16* Wl = Wh + 3 * 16384;                   // 3*128*128 halfs, fragment-major

    // zero counts + stats every call (single contiguous memset)
    hipMemsetAsync(cnt_f, 0, (size_t)(2 * N + 2 * D) * sizeof(float), stream);

    // fp16 hi/lo conversion of the 3 entity-side weight matrices (W_S, W_O, W_I)
    convert_w_kernel<<<24, 256, 0, stream>>>(W_S, W_O, W_I, Wh, Wl);

    // MFMA triple GEMM (LDS-staged A, frag-major B): self-loop fp32 into out acc,
    // HO/HI stored fp16 for the bandwidth-bound gather
    const int gemm_grid_ent = (N + 63) / 64;
    gemm3_mfma_kernel<<<gemm_grid_ent, 256, 0, stream>>>(ent, Wh, Wl, acc, HO, HI, N);

    // relation projections (tiny, fp32 path) + new_rel_emb output
    const int gemm_grid_rel = (R + 63) / 64;
    gemm3_nt_kernel<<<gemm_grid_rel, 256, 0, stream>>>(rel, W_O, W_I, W_rel,
                                                       RO, RI, outp + (size_t)N * D, R);

    // CSR build: histogram -> hierarchical scan -> XCD-cohort fill
    hist_kernel<<<1024, 256, 0, stream>>>(eidx, cnt_f, cnt_i, E);
    const int scan_blocks = (2 * N + 511) / 512;   // 196 for N=50000 (must be <= 256)
    scan_p1_kernel<<<scan_blocks, 256, 0, stream>>>(cnt_f, bsum, 2 * N);
    scan_p2_kernel<<<1, 256, 0, stream>>>(bsum, boff, scan_blocks);
    scan_p3_kernel<<<scan_blocks, 256, 0, stream>>>(cnt_f, boff,
                                                    off_f, cur_f, off_i, cur_i, N, E);
    fill_kernel<<<2048, 256, 0, stream>>>(eidx, etype, cur_f, cur_i, pay_f, pay_i, E, N);

    // pull-gather (one wave per node) -> degree-normalized pre-BN x in d_out
    const int gather_blocks = (int)(((size_t)N * 64 + 255) / 256);
    gather_kernel<<<gather_blocks, 256, 0, stream>>>(
        off_f, pay_f, off_i, pay_i, HO, HI, RO, RI, acc, N);

    // column stats of x
    stats_kernel<<<1024, 256, 0, stream>>>(acc, gsum, gsq, N);

    // BN + ReLU in place
    bn_relu_kernel<<<2048, 256, 0, stream>>>(outp, gsum, gsq, gamma, beta, N);
}